// Round 15
// baseline (194.629 us; speedup 1.0000x reference)
//
#include <hip/hip_runtime.h>
#include <hip/hip_bf16.h>
#include <math.h>

// Problem constants (B=2, T=2048, C=1024, NH=16, HS=64)
#define BB   2
#define TT   2048
#define CC   1024
#define NH   16
#define HS   64
#define N3C  3072   // 3*C
#define MM   4096   // B*T

typedef __attribute__((ext_vector_type(8))) short bf16x8;
typedef __attribute__((ext_vector_type(4))) float f32x4;

#define NINF (-__builtin_inff())
// QSCALE = 1/sqrt(HS) * log2(e): softmax computed in exp2 domain
// (2^(x*0.125*log2e) == e^(x*0.125), exact identity).
#define QSCALE 0.180336879f

__device__ __forceinline__ unsigned short f2bf(float f) {
    unsigned int u = __builtin_bit_cast(unsigned int, f);
    unsigned int r = u + 0x7fffu + ((u >> 16) & 1u);   // RNE
    return (unsigned short)(r >> 16);
}

// cheap round-to-nearest (no tie-to-even) — used only for P (positive, bounded)
__device__ __forceinline__ unsigned short f2bf_fast(float f) {
    unsigned int u = __builtin_bit_cast(unsigned int, f);
    return (unsigned short)((u + 0x8000u) >> 16);
}

// async 16B global -> LDS (dst must be wave-uniform base + lane*16)
__device__ __forceinline__ void gl_lds16(const unsigned short* g, unsigned short* l) {
    __builtin_amdgcn_global_load_lds(
        (const __attribute__((address_space(1))) unsigned int*)g,
        (__attribute__((address_space(3))) unsigned int*)l, 16, 0, 0);
}

// ---------------- cast x (fp32) -> xb (bf16) ----------------
__global__ __launch_bounds__(256) void k_cast(const float* __restrict__ x,
                                              unsigned short* __restrict__ xb) {
    int i = (blockIdx.x * 256 + threadIdx.x) * 4;
    float4 v = *(const float4*)(x + i);
    ushort4 o;
    o.x = f2bf(v.x); o.y = f2bf(v.y); o.z = f2bf(v.z); o.w = f2bf(v.w);
    *(ushort4*)(xb + i) = o;
}

// ---------------- transpose+cast W [K=1024, N=3072] -> Wt [N, K] bf16 ----------------
__global__ __launch_bounds__(256) void k_transpose_w(const float* __restrict__ W,
                                                     unsigned short* __restrict__ Wt) {
    __shared__ float tile[32][33];
    const int n0 = blockIdx.x * 32;
    const int k0 = blockIdx.y * 32;
    const int t = threadIdx.x;
    {
        int kr = t >> 3, ns = (t & 7) * 4;
        float4 v = *(const float4*)(W + (size_t)(k0 + kr) * N3C + n0 + ns);
        tile[kr][ns + 0] = v.x; tile[kr][ns + 1] = v.y;
        tile[kr][ns + 2] = v.z; tile[kr][ns + 3] = v.w;
    }
    __syncthreads();
    {
        int nr = t >> 3, ks = (t & 7) * 4;
        ushort4 o;
        o.x = f2bf(tile[ks + 0][nr]);
        o.y = f2bf(tile[ks + 1][nr]);
        o.z = f2bf(tile[ks + 2][nr]);
        o.w = f2bf(tile[ks + 3][nr]);
        *(ushort4*)(Wt + (size_t)(n0 + nr) * CC + k0 + ks) = o;
    }
}

// ---------------- GEMM v3 (r11-proven EXACT, no setprio): counted-vmcnt double-buffer. ----------------
#define EPS 72   // epilogue LDS row stride (elements): 144B, 16B-aligned

__global__ __launch_bounds__(256) void k_gemm_qkv(const unsigned short* __restrict__ xb,
                                                  const unsigned short* __restrict__ wt,
                                                  const float* __restrict__ bias,
                                                  unsigned short* __restrict__ qb,
                                                  unsigned short* __restrict__ kb,
                                                  unsigned short* __restrict__ vt) {
    __shared__ unsigned short smem[32768];          // 64 KB: 2 bufs x (sA 8192 + sB 8192 elems)
    unsigned short* sE = smem;                      // 4 x [64][EPS] epilogue staging (36 KB, union)

    const int t = threadIdx.x;
    const int wave = t >> 6, lane = t & 63;
    const int quad = lane >> 4, c16 = lane & 15;
    const int wm = wave >> 1, wn = wave & 1;
    const int m0 = blockIdx.y * 128;
    const int n0 = blockIdx.x * 128;
    const int sel = n0 >> 10;                 // block-uniform: 0=q, 1=k, 2=v

    f32x4 acc[4][4];
#pragma unroll
    for (int i = 0; i < 4; ++i)
#pragma unroll
        for (int j = 0; j < 4; ++j) acc[i][j] = f32x4{0, 0, 0, 0};

    const int srow_ = t >> 3;                 // 0..31 (row within a 32-row round)
    const int sslot = t & 7;                  // 16B slot within 128B row

    // stage k-tile (BK=64) into buffer b: LINEAR LDS dest, XOR-swizzled GLOBAL source
    auto stage = [&](int b, int k0) {
        unsigned short* dA = smem + b * 16384;
        unsigned short* dB = smem + b * 16384 + 8192;
#pragma unroll
        for (int rnd = 0; rnd < 4; ++rnd) {
            const int row = rnd * 32 + srow_;
            const int sl = (sslot ^ (row & 7)) * 8;           // pre-swizzled global elem offset
            gl_lds16(xb + (size_t)(m0 + row) * CC + k0 + sl, dA + rnd * 2048 + t * 8);
            gl_lds16(wt + (size_t)(n0 + row) * CC + k0 + sl, dB + rnd * 2048 + t * 8);
        }
    };

    stage(0, 0);
    for (int it = 0; it < 16; ++it) {
        if (it + 1 < 16) {
            stage((it + 1) & 1, (it + 1) * 64);
            asm volatile("s_waitcnt vmcnt(8)" ::: "memory");   // wait stage(it) only
        } else {
            asm volatile("s_waitcnt vmcnt(0)" ::: "memory");
        }
        __builtin_amdgcn_s_barrier();
        asm volatile("" ::: "memory");
        const unsigned short* sA = smem + (it & 1) * 16384;
        const unsigned short* sB = smem + (it & 1) * 16384 + 8192;
#pragma unroll
        for (int ks = 0; ks < 2; ++ks) {
            bf16x8 a[4], b[4];
#pragma unroll
            for (int rt = 0; rt < 4; ++rt)
                a[rt] = *(const bf16x8*)(sA + (wm * 64 + rt * 16 + c16) * 64 +
                                         (((ks * 4 + quad) ^ (c16 & 7)) * 8));
#pragma unroll
            for (int ct = 0; ct < 4; ++ct)
                b[ct] = *(const bf16x8*)(sB + (wn * 64 + ct * 16 + c16) * 64 +
                                         (((ks * 4 + quad) ^ (c16 & 7)) * 8));
#pragma unroll
            for (int rt = 0; rt < 4; ++rt)
#pragma unroll
                for (int ct = 0; ct < 4; ++ct)
                    acc[rt][ct] = __builtin_amdgcn_mfma_f32_16x16x32_bf16(b[ct], a[rt], acc[rt][ct], 0, 0, 0);
        }
        __builtin_amdgcn_s_barrier();          // protect buf (it+1)&1 from next stage overwrite
        asm volatile("" ::: "memory");
    }
    __syncthreads();   // union: epilogue sE overlaps the k-loop buffers

    const int head = ((n0 + wn * 64) >> 6) & 15;           // wave-uniform
    const int bh = (m0 >> 11) * NH + head;
    const int tbase = (m0 & 2047) + wm * 64;               // this wave's 64 t-rows
    if (sel < 2) {
        unsigned short* dst = (sel == 0) ? qb : kb;
        const float sc = (sel == 0) ? QSCALE : 1.0f;       // QSCALE includes log2(e) fold
        unsigned short* ew = sE + wave * (64 * EPS);
#pragma unroll
        for (int ct = 0; ct < 4; ++ct) {
            const float4 bv4 = *(const float4*)(bias + n0 + wn * 64 + ct * 16 + quad * 4);
            const int d0 = ct * 16 + quad * 4;
#pragma unroll
            for (int rt = 0; rt < 4; ++rt) {
                ushort4 pk;
                pk.x = f2bf((acc[rt][ct][0] + bv4.x) * sc);
                pk.y = f2bf((acc[rt][ct][1] + bv4.y) * sc);
                pk.z = f2bf((acc[rt][ct][2] + bv4.z) * sc);
                pk.w = f2bf((acc[rt][ct][3] + bv4.w) * sc);
                *(ushort4*)(ew + (rt * 16 + c16) * EPS + d0) = pk;
            }
        }
        const size_t gbase = ((size_t)bh * TT + tbase) * HS;
#pragma unroll
        for (int i = 0; i < 8; ++i) {
            const int trow = i * 8 + (lane >> 3);
            bf16x8 row = *(const bf16x8*)(ew + trow * EPS + (lane & 7) * 8);
            *(bf16x8*)(dst + gbase + (size_t)trow * HS + (lane & 7) * 8) = row;
        }
    } else {
        unsigned short* ew = sE + wave * (64 * EPS);
#pragma unroll
        for (int ct = 0; ct < 4; ++ct) {
            const float4 bv4 = *(const float4*)(bias + n0 + wn * 64 + ct * 16 + quad * 4);
#pragma unroll
            for (int r = 0; r < 4; ++r) {
                const int d = ct * 16 + quad * 4 + r;
                const float bv = ((const float*)&bv4)[r];
#pragma unroll
                for (int rt = 0; rt < 4; ++rt)
                    ew[d * EPS + rt * 16 + c16] = f2bf(acc[rt][ct][r] + bv);
            }
        }
        const size_t vbase = (size_t)bh * HS * TT + tbase;
#pragma unroll
        for (int i = 0; i < 8; ++i) {
            const int d = i * 8 + (lane >> 3);
            bf16x8 row = *(const bf16x8*)(ew + d * EPS + (lane & 7) * 8);
            *(bf16x8*)(vt + vbase + (size_t)d * TT + (lane & 7) * 8) = row;
        }
    }
}

// ---------------- Flash attention v17 = r12 v15 with V-staging DROPPED.
// Evidence: wave slots are the proven lever (r10: 8->12 waves/CU = -4us); occupancy
// still only 22%. V (16MB total, per-XCD ~2MB working set) is L2-resident -- staging
// L2-fit data is pure overhead (guide CM#7: dropping V-staging was +26% there).
// Removing sV: LDS 41984 -> 25600 B -> 6 blocks/CU = 24 waves/CU (2x slots), and
// staging DMA halves. vf fragments revert to DIRECT GLOBAL loads with the round-0
// proven-correct indexing (lifted verbatim), issued at tile start so L2 latency
// hides under kf ds_reads + S-MFMA + softmax. Stage = K only -> vmcnt(2). ----------------
#define SPP 72   // P row stride (elements): 144B, 16B-aligned

__global__ __launch_bounds__(256) void k_attn(const unsigned short* __restrict__ qb,
                                              const unsigned short* __restrict__ kb,
                                              const unsigned short* __restrict__ vt,
                                              float* __restrict__ out) {
    __shared__ unsigned short sK[2][64 * 64];   // 16 KB: K tile [row t][d], granule-swizzled
    __shared__ unsigned short sP[4][16 * SPP];  // 9 KB: per-wave P staging (16 rows each)
    // total 25600 B -> 6 blocks/CU

    const int tid = threadIdx.x;
    const int wave = tid >> 6, lane = tid & 63;
    const int quad = lane >> 4, c16 = lane & 15;
    const int hp = 31 - (int)(blockIdx.x >> 5); // half-panel 0..31, longest work first
    const int bh = blockIdx.x & 31;

    const unsigned short* Qp = qb + (size_t)bh * TT * HS;
    const unsigned short* Kp = kb + (size_t)bh * TT * HS;
    const unsigned short* Vp = vt + (size_t)bh * HS * TT;

    unsigned short* sPw = sP[wave];

    // --- staging (K only): 256 threads cover 64 rows x 8 slots of 16B in 2 rounds;
    // 2 loads per thread per tile. LDS dest LINEAR; XOR swizzle on GLOBAL source.
    const int srow = tid >> 3;                  // 0..31 (row within round)
    const int ssc = tid & 7;                    // 16B slot
    const int sl = (ssc ^ (srow & 7)) * 8;      // swizzled elem offset ((rnd*32+srow)&7 == srow&7)
    auto stage = [&](int buf, int kt) {
        const int kb0 = kt * 64;
#pragma unroll
        for (int rnd = 0; rnd < 2; ++rnd) {
            const int row = rnd * 32 + srow;
            gl_lds16(Kp + (size_t)(kb0 + row) * HS + sl, &sK[buf][rnd * 2048 + tid * 8]);
        }
    };

    const int b_ = bh >> 4, h_ = bh & 15;
    const int qw = hp * 64 + wave * 16;         // this wave's 16 q-rows
    const int kiters = hp + 1;                  // k-tiles 0..hp cover k <= hp*64+63

    bf16x8 qf[2];
#pragma unroll
    for (int ks = 0; ks < 2; ++ks)
        qf[ks] = *(const bf16x8*)(Qp + (size_t)(qw + c16) * HS + ks * 32 + quad * 8);

    // V direct-global base (round-0 proven indexing): lane reads vt[bh][dt*16+c16][kb0+quad*8..]
    const unsigned short* vbase = Vp + (size_t)c16 * TT + quad * 8;

    f32x4 o[4];
#pragma unroll
    for (int dt = 0; dt < 4; ++dt) o[dt] = f32x4{0, 0, 0, 0};
    float lsum = 0.f;

    auto tile = [&](int buf, int kt) {
        const int kb0 = kt * 64;
        const unsigned short* Kb = sK[buf];
        // V loads issued up front (global, L2-hit); consumed only after softmax -> hidden
        bf16x8 vf[4][2];
#pragma unroll
        for (int dt = 0; dt < 4; ++dt) {
            vf[dt][0] = *(const bf16x8*)(vbase + (size_t)dt * 16 * TT + kb0);
            vf[dt][1] = *(const bf16x8*)(vbase + (size_t)dt * 16 * TT + kb0 + 32);
        }
        bf16x8 kf[4][2];
#pragma unroll
        for (int mt = 0; mt < 4; ++mt)
#pragma unroll
            for (int ks = 0; ks < 2; ++ks)
                kf[mt][ks] = *(const bf16x8*)(Kb + (mt * 16 + c16) * 64 +
                                              (((ks * 4 + quad) ^ (c16 & 7)) * 8));
        f32x4 s[4];
#pragma unroll
        for (int mt = 0; mt < 4; ++mt) s[mt] = f32x4{0, 0, 0, 0};
        __builtin_amdgcn_s_setprio(1);
#pragma unroll
        for (int mt = 0; mt < 4; ++mt) {
            s[mt] = __builtin_amdgcn_mfma_f32_16x16x32_bf16(kf[mt][0], qf[0], s[mt], 0, 0, 0);
            s[mt] = __builtin_amdgcn_mfma_f32_16x16x32_bf16(kf[mt][1], qf[1], s[mt], 0, 0, 0);
        }
        __builtin_amdgcn_s_setprio(0);
        const bool maskit = (kb0 + 63 > qw);
        const int rowq = qw + c16;
        float l = 0.f;
#pragma unroll
        for (int mt = 0; mt < 4; ++mt) {
            float p0, p1, p2, p3;
            if (maskit) {
                const int k = kb0 + mt * 16 + quad * 4;
                p0 = __builtin_amdgcn_exp2f((k     <= rowq) ? s[mt][0] : NINF);
                p1 = __builtin_amdgcn_exp2f((k + 1 <= rowq) ? s[mt][1] : NINF);
                p2 = __builtin_amdgcn_exp2f((k + 2 <= rowq) ? s[mt][2] : NINF);
                p3 = __builtin_amdgcn_exp2f((k + 3 <= rowq) ? s[mt][3] : NINF);
            } else {
                p0 = __builtin_amdgcn_exp2f(s[mt][0]);
                p1 = __builtin_amdgcn_exp2f(s[mt][1]);
                p2 = __builtin_amdgcn_exp2f(s[mt][2]);
                p3 = __builtin_amdgcn_exp2f(s[mt][3]);
            }
            l += (p0 + p1) + (p2 + p3);
            ushort4 pk;
            pk.x = f2bf_fast(p0); pk.y = f2bf_fast(p1);
            pk.z = f2bf_fast(p2); pk.w = f2bf_fast(p3);
            *(ushort4*)(sPw + c16 * SPP + mt * 16 + quad * 4) = pk;
        }
        lsum += l;
        bf16x8 pf[2];
#pragma unroll
        for (int ks = 0; ks < 2; ++ks)
            pf[ks] = *(const bf16x8*)(sPw + c16 * SPP + ks * 32 + quad * 8);
        __builtin_amdgcn_s_setprio(1);
#pragma unroll
        for (int dt = 0; dt < 4; ++dt) {
            o[dt] = __builtin_amdgcn_mfma_f32_16x16x32_bf16(vf[dt][0], pf[0], o[dt], 0, 0, 0);
            o[dt] = __builtin_amdgcn_mfma_f32_16x16x32_bf16(vf[dt][1], pf[1], o[dt], 0, 0, 0);
        }
        __builtin_amdgcn_s_setprio(0);
    };

    stage(0, 0);
    for (int kt = 0; kt < kiters; ++kt) {
        if (kt + 1 < kiters) {
            stage((kt + 1) & 1, kt + 1);
            asm volatile("s_waitcnt vmcnt(2)" ::: "memory");   // wait stage(kt)'s K loads only
        } else {
            asm volatile("s_waitcnt vmcnt(0)" ::: "memory");
        }
        __builtin_amdgcn_s_barrier();
        asm volatile("" ::: "memory");
        tile(kt & 1, kt);                       // no tiles skipped: all kt <= hp needed
        __builtin_amdgcn_s_barrier();
        asm volatile("" ::: "memory");
    }

    lsum += __shfl_xor(lsum, 16);
    lsum += __shfl_xor(lsum, 32);

    const float il = 1.0f / lsum;
    const int q = qw + c16;
    float* orow = out + ((size_t)(b_ * TT + q)) * CC + h_ * HS;
#pragma unroll
    for (int dt = 0; dt < 4; ++dt) {
        float4 w;
        w.x = o[dt][0] * il; w.y = o[dt][1] * il;
        w.z = o[dt][2] * il; w.w = o[dt][3] * il;
        *(float4*)(orow + dt * 16 + quad * 4) = w;
    }
}

extern "C" void kernel_launch(void* const* d_in, const int* in_sizes, int n_in,
                              void* d_out, int out_size, void* d_ws, size_t ws_size,
                              hipStream_t stream) {
    const float* x    = (const float*)d_in[0];   // [B,T,C] fp32
    const float* W    = (const float*)d_in[1];   // [C,3C] fp32
    const float* bias = (const float*)d_in[2];   // [3C] fp32
    float* out = (float*)d_out;                  // [B,T,C] fp32

    char* ws = (char*)d_ws;
    unsigned short* xb = (unsigned short*)(ws);
    unsigned short* wt = (unsigned short*)(ws + 8388608);
    unsigned short* qb = (unsigned short*)(ws + 8388608 + 6291456);
    unsigned short* kb = (unsigned short*)(ws + 8388608 + 6291456 + 8388608);
    unsigned short* vt = (unsigned short*)(ws + 8388608 + 6291456 + 2 * 8388608);

    k_cast<<<dim3(MM * CC / (256 * 4)), dim3(256), 0, stream>>>(x, xb);
    k_transpose_w<<<dim3(N3C / 32, CC / 32), dim3(256), 0, stream>>>(W, wt);
    k_gemm_qkv<<<dim3(N3C / 128, MM / 128), dim3(256), 0, stream>>>(xb, wt, bias, qb, kb, vt);
    k_attn<<<dim3(32 * 32), dim3(256), 0, stream>>>(qb, kb, vt, out);
}

// Round 16
// 150.486 us; speedup vs baseline: 1.2933x; 1.2933x over previous
//
#include <hip/hip_runtime.h>
#include <hip/hip_bf16.h>
#include <math.h>

// Problem constants (B=2, T=2048, C=1024, NH=16, HS=64)
#define BB   2
#define TT   2048
#define CC   1024
#define NH   16
#define HS   64
#define N3C  3072   // 3*C
#define MM   4096   // B*T

typedef __attribute__((ext_vector_type(8))) short bf16x8;
typedef __attribute__((ext_vector_type(4))) float f32x4;

#define NINF (-__builtin_inff())
// QSCALE = 1/sqrt(HS) * log2(e): softmax computed in exp2 domain
// (2^(x*0.125*log2e) == e^(x*0.125), exact identity).
#define QSCALE 0.180336879f

__device__ __forceinline__ unsigned short f2bf(float f) {
    unsigned int u = __builtin_bit_cast(unsigned int, f);
    unsigned int r = u + 0x7fffu + ((u >> 16) & 1u);   // RNE
    return (unsigned short)(r >> 16);
}

// cheap round-to-nearest (no tie-to-even) — used only for P (positive, bounded)
__device__ __forceinline__ unsigned short f2bf_fast(float f) {
    unsigned int u = __builtin_bit_cast(unsigned int, f);
    return (unsigned short)((u + 0x8000u) >> 16);
}

// async 16B global -> LDS (dst must be wave-uniform base + lane*16)
__device__ __forceinline__ void gl_lds16(const unsigned short* g, unsigned short* l) {
    __builtin_amdgcn_global_load_lds(
        (const __attribute__((address_space(1))) unsigned int*)g,
        (__attribute__((address_space(3))) unsigned int*)l, 16, 0, 0);
}

// ---------------- cast x (fp32) -> xb (bf16) ----------------
__global__ __launch_bounds__(256) void k_cast(const float* __restrict__ x,
                                              unsigned short* __restrict__ xb) {
    int i = (blockIdx.x * 256 + threadIdx.x) * 4;
    float4 v = *(const float4*)(x + i);
    ushort4 o;
    o.x = f2bf(v.x); o.y = f2bf(v.y); o.z = f2bf(v.z); o.w = f2bf(v.w);
    *(ushort4*)(xb + i) = o;
}

// ---------------- transpose+cast W [K=1024, N=3072] -> Wt [N, K] bf16 ----------------
__global__ __launch_bounds__(256) void k_transpose_w(const float* __restrict__ W,
                                                     unsigned short* __restrict__ Wt) {
    __shared__ float tile[32][33];
    const int n0 = blockIdx.x * 32;
    const int k0 = blockIdx.y * 32;
    const int t = threadIdx.x;
    {
        int kr = t >> 3, ns = (t & 7) * 4;
        float4 v = *(const float4*)(W + (size_t)(k0 + kr) * N3C + n0 + ns);
        tile[kr][ns + 0] = v.x; tile[kr][ns + 1] = v.y;
        tile[kr][ns + 2] = v.z; tile[kr][ns + 3] = v.w;
    }
    __syncthreads();
    {
        int nr = t >> 3, ks = (t & 7) * 4;
        ushort4 o;
        o.x = f2bf(tile[ks + 0][nr]);
        o.y = f2bf(tile[ks + 1][nr]);
        o.z = f2bf(tile[ks + 2][nr]);
        o.w = f2bf(tile[ks + 3][nr]);
        *(ushort4*)(Wt + (size_t)(n0 + nr) * CC + k0 + ks) = o;
    }
}

// ---------------- GEMM v3 (r11-proven EXACT, no setprio): counted-vmcnt double-buffer.
// Evidence: best GEMM measured (~36us); r12's setprio variant regressed (lockstep
// pipeline, matches m190 null/negative on barrier-synced GEMM). ----------------
#define EPS 72   // epilogue LDS row stride (elements): 144B, 16B-aligned

__global__ __launch_bounds__(256) void k_gemm_qkv(const unsigned short* __restrict__ xb,
                                                  const unsigned short* __restrict__ wt,
                                                  const float* __restrict__ bias,
                                                  unsigned short* __restrict__ qb,
                                                  unsigned short* __restrict__ kb,
                                                  unsigned short* __restrict__ vt) {
    __shared__ unsigned short smem[32768];          // 64 KB: 2 bufs x (sA 8192 + sB 8192 elems)
    unsigned short* sE = smem;                      // 4 x [64][EPS] epilogue staging (36 KB, union)

    const int t = threadIdx.x;
    const int wave = t >> 6, lane = t & 63;
    const int quad = lane >> 4, c16 = lane & 15;
    const int wm = wave >> 1, wn = wave & 1;
    const int m0 = blockIdx.y * 128;
    const int n0 = blockIdx.x * 128;
    const int sel = n0 >> 10;                 // block-uniform: 0=q, 1=k, 2=v

    f32x4 acc[4][4];
#pragma unroll
    for (int i = 0; i < 4; ++i)
#pragma unroll
        for (int j = 0; j < 4; ++j) acc[i][j] = f32x4{0, 0, 0, 0};

    const int srow_ = t >> 3;                 // 0..31 (row within a 32-row round)
    const int sslot = t & 7;                  // 16B slot within 128B row

    // stage k-tile (BK=64) into buffer b: LINEAR LDS dest, XOR-swizzled GLOBAL source
    auto stage = [&](int b, int k0) {
        unsigned short* dA = smem + b * 16384;
        unsigned short* dB = smem + b * 16384 + 8192;
#pragma unroll
        for (int rnd = 0; rnd < 4; ++rnd) {
            const int row = rnd * 32 + srow_;
            const int sl = (sslot ^ (row & 7)) * 8;           // pre-swizzled global elem offset
            gl_lds16(xb + (size_t)(m0 + row) * CC + k0 + sl, dA + rnd * 2048 + t * 8);
            gl_lds16(wt + (size_t)(n0 + row) * CC + k0 + sl, dB + rnd * 2048 + t * 8);
        }
    };

    stage(0, 0);
    for (int it = 0; it < 16; ++it) {
        if (it + 1 < 16) {
            stage((it + 1) & 1, (it + 1) * 64);
            asm volatile("s_waitcnt vmcnt(8)" ::: "memory");   // wait stage(it) only
        } else {
            asm volatile("s_waitcnt vmcnt(0)" ::: "memory");
        }
        __builtin_amdgcn_s_barrier();
        asm volatile("" ::: "memory");
        const unsigned short* sA = smem + (it & 1) * 16384;
        const unsigned short* sB = smem + (it & 1) * 16384 + 8192;
#pragma unroll
        for (int ks = 0; ks < 2; ++ks) {
            bf16x8 a[4], b[4];
#pragma unroll
            for (int rt = 0; rt < 4; ++rt)
                a[rt] = *(const bf16x8*)(sA + (wm * 64 + rt * 16 + c16) * 64 +
                                         (((ks * 4 + quad) ^ (c16 & 7)) * 8));
#pragma unroll
            for (int ct = 0; ct < 4; ++ct)
                b[ct] = *(const bf16x8*)(sB + (wn * 64 + ct * 16 + c16) * 64 +
                                         (((ks * 4 + quad) ^ (c16 & 7)) * 8));
#pragma unroll
            for (int rt = 0; rt < 4; ++rt)
#pragma unroll
                for (int ct = 0; ct < 4; ++ct)
                    acc[rt][ct] = __builtin_amdgcn_mfma_f32_16x16x32_bf16(b[ct], a[rt], acc[rt][ct], 0, 0, 0);
        }
        __builtin_amdgcn_s_barrier();          // protect buf (it+1)&1 from next stage overwrite
        asm volatile("" ::: "memory");
    }
    __syncthreads();   // union: epilogue sE overlaps the k-loop buffers

    const int head = ((n0 + wn * 64) >> 6) & 15;           // wave-uniform
    const int bh = (m0 >> 11) * NH + head;
    const int tbase = (m0 & 2047) + wm * 64;               // this wave's 64 t-rows
    if (sel < 2) {
        unsigned short* dst = (sel == 0) ? qb : kb;
        const float sc = (sel == 0) ? QSCALE : 1.0f;       // QSCALE includes log2(e) fold
        unsigned short* ew = sE + wave * (64 * EPS);
#pragma unroll
        for (int ct = 0; ct < 4; ++ct) {
            const float4 bv4 = *(const float4*)(bias + n0 + wn * 64 + ct * 16 + quad * 4);
            const int d0 = ct * 16 + quad * 4;
#pragma unroll
            for (int rt = 0; rt < 4; ++rt) {
                ushort4 pk;
                pk.x = f2bf((acc[rt][ct][0] + bv4.x) * sc);
                pk.y = f2bf((acc[rt][ct][1] + bv4.y) * sc);
                pk.z = f2bf((acc[rt][ct][2] + bv4.z) * sc);
                pk.w = f2bf((acc[rt][ct][3] + bv4.w) * sc);
                *(ushort4*)(ew + (rt * 16 + c16) * EPS + d0) = pk;
            }
        }
        const size_t gbase = ((size_t)bh * TT + tbase) * HS;
#pragma unroll
        for (int i = 0; i < 8; ++i) {
            const int trow = i * 8 + (lane >> 3);
            bf16x8 row = *(const bf16x8*)(ew + trow * EPS + (lane & 7) * 8);
            *(bf16x8*)(dst + gbase + (size_t)trow * HS + (lane & 7) * 8) = row;
        }
    } else {
        unsigned short* ew = sE + wave * (64 * EPS);
#pragma unroll
        for (int ct = 0; ct < 4; ++ct) {
            const float4 bv4 = *(const float4*)(bias + n0 + wn * 64 + ct * 16 + quad * 4);
#pragma unroll
            for (int r = 0; r < 4; ++r) {
                const int d = ct * 16 + quad * 4 + r;
                const float bv = ((const float*)&bv4)[r];
#pragma unroll
                for (int rt = 0; rt < 4; ++rt)
                    ew[d * EPS + rt * 16 + c16] = f2bf(acc[rt][ct][r] + bv);
            }
        }
        const size_t vbase = (size_t)bh * HS * TT + tbase;
#pragma unroll
        for (int i = 0; i < 8; ++i) {
            const int d = i * 8 + (lane >> 3);
            bf16x8 row = *(const bf16x8*)(ew + d * EPS + (lane & 7) * 8);
            *(bf16x8*)(vt + vbase + (size_t)d * TT + (lane & 7) * 8) = row;
        }
    }
}

// ---------------- Flash attention v15 (r12/r14-proven EXACT, 44.9-45.1us): 1024
// four-wave half-panel blocks (3 blocks/CU = 12 waves/CU), K AND V staged in LDS
// (r15 proved V-staging is NOT overhead: V-in-LDS keeps the O-MFMA fed via ~120cyc
// conflict-free ds_reads; direct-global V doubled the kernel time), counted-vmcnt
// double-buffer, exp2-domain softmax, setprio around S/O MFMA clusters. ----------------
#define SPP 72   // P row stride (elements): 144B, 16B-aligned

__global__ __launch_bounds__(256) void k_attn(const unsigned short* __restrict__ qb,
                                              const unsigned short* __restrict__ kb,
                                              const unsigned short* __restrict__ vt,
                                              float* __restrict__ out) {
    __shared__ unsigned short sK[2][64 * 64];   // 16 KB: K tile [row t][d], granule-swizzled
    __shared__ unsigned short sV[2][64 * 64];   // 16 KB: V^T tile [row d][t], granule-swizzled
    __shared__ unsigned short sP[4][16 * SPP];  // 9 KB: per-wave P staging (16 rows each)

    const int tid = threadIdx.x;
    const int wave = tid >> 6, lane = tid & 63;
    const int quad = lane >> 4, c16 = lane & 15;
    const int hp = 31 - (int)(blockIdx.x >> 5); // half-panel 0..31, longest work first
    const int bh = blockIdx.x & 31;

    const unsigned short* Qp = qb + (size_t)bh * TT * HS;
    const unsigned short* Kp = kb + (size_t)bh * TT * HS;
    const unsigned short* Vp = vt + (size_t)bh * HS * TT;

    unsigned short* sPw = sP[wave];

    const int srow = tid >> 3;                  // 0..31 (row within round)
    const int ssc = tid & 7;                    // 16B slot
    const int sl = (ssc ^ (srow & 7)) * 8;      // swizzled elem offset ((rnd*32+srow)&7 == srow&7)
    auto stage = [&](int buf, int kt) {
        const int kb0 = kt * 64;
#pragma unroll
        for (int rnd = 0; rnd < 2; ++rnd) {
            const int row = rnd * 32 + srow;
            gl_lds16(Kp + (size_t)(kb0 + row) * HS + sl, &sK[buf][rnd * 2048 + tid * 8]);
            gl_lds16(Vp + (size_t)row * TT + kb0 + sl, &sV[buf][rnd * 2048 + tid * 8]);
        }
    };

    const int b_ = bh >> 4, h_ = bh & 15;
    const int qw = hp * 64 + wave * 16;         // this wave's 16 q-rows
    const int kiters = hp + 1;                  // k-tiles 0..hp cover k <= hp*64+63

    bf16x8 qf[2];
#pragma unroll
    for (int ks = 0; ks < 2; ++ks)
        qf[ks] = *(const bf16x8*)(Qp + (size_t)(qw + c16) * HS + ks * 32 + quad * 8);

    f32x4 o[4];
#pragma unroll
    for (int dt = 0; dt < 4; ++dt) o[dt] = f32x4{0, 0, 0, 0};
    float lsum = 0.f;

    auto tile = [&](int buf, int kt) {
        const int kb0 = kt * 64;
        const unsigned short* Kb = sK[buf];
        const unsigned short* Vb = sV[buf];
        bf16x8 kf[4][2];
#pragma unroll
        for (int mt = 0; mt < 4; ++mt)
#pragma unroll
            for (int ks = 0; ks < 2; ++ks)
                kf[mt][ks] = *(const bf16x8*)(Kb + (mt * 16 + c16) * 64 +
                                              (((ks * 4 + quad) ^ (c16 & 7)) * 8));
        f32x4 s[4];
#pragma unroll
        for (int mt = 0; mt < 4; ++mt) s[mt] = f32x4{0, 0, 0, 0};
        __builtin_amdgcn_s_setprio(1);
#pragma unroll
        for (int mt = 0; mt < 4; ++mt) {
            s[mt] = __builtin_amdgcn_mfma_f32_16x16x32_bf16(kf[mt][0], qf[0], s[mt], 0, 0, 0);
            s[mt] = __builtin_amdgcn_mfma_f32_16x16x32_bf16(kf[mt][1], qf[1], s[mt], 0, 0, 0);
        }
        __builtin_amdgcn_s_setprio(0);
        bf16x8 vf[4][2];
#pragma unroll
        for (int dt = 0; dt < 4; ++dt)
#pragma unroll
            for (int ks = 0; ks < 2; ++ks)
                vf[dt][ks] = *(const bf16x8*)(Vb + (dt * 16 + c16) * 64 +
                                              (((ks * 4 + quad) ^ (c16 & 7)) * 8));
        const bool maskit = (kb0 + 63 > qw);
        const int rowq = qw + c16;
        float l = 0.f;
#pragma unroll
        for (int mt = 0; mt < 4; ++mt) {
            float p0, p1, p2, p3;
            if (maskit) {
                const int k = kb0 + mt * 16 + quad * 4;
                p0 = __builtin_amdgcn_exp2f((k     <= rowq) ? s[mt][0] : NINF);
                p1 = __builtin_amdgcn_exp2f((k + 1 <= rowq) ? s[mt][1] : NINF);
                p2 = __builtin_amdgcn_exp2f((k + 2 <= rowq) ? s[mt][2] : NINF);
                p3 = __builtin_amdgcn_exp2f((k + 3 <= rowq) ? s[mt][3] : NINF);
            } else {
                p0 = __builtin_amdgcn_exp2f(s[mt][0]);
                p1 = __builtin_amdgcn_exp2f(s[mt][1]);
                p2 = __builtin_amdgcn_exp2f(s[mt][2]);
                p3 = __builtin_amdgcn_exp2f(s[mt][3]);
            }
            l += (p0 + p1) + (p2 + p3);
            ushort4 pk;
            pk.x = f2bf_fast(p0); pk.y = f2bf_fast(p1);
            pk.z = f2bf_fast(p2); pk.w = f2bf_fast(p3);
            *(ushort4*)(sPw + c16 * SPP + mt * 16 + quad * 4) = pk;
        }
        lsum += l;
        bf16x8 pf[2];
#pragma unroll
        for (int ks = 0; ks < 2; ++ks)
            pf[ks] = *(const bf16x8*)(sPw + c16 * SPP + ks * 32 + quad * 8);
        __builtin_amdgcn_s_setprio(1);
#pragma unroll
        for (int dt = 0; dt < 4; ++dt) {
            o[dt] = __builtin_amdgcn_mfma_f32_16x16x32_bf16(vf[dt][0], pf[0], o[dt], 0, 0, 0);
            o[dt] = __builtin_amdgcn_mfma_f32_16x16x32_bf16(vf[dt][1], pf[1], o[dt], 0, 0, 0);
        }
        __builtin_amdgcn_s_setprio(0);
    };

    stage(0, 0);
    for (int kt = 0; kt < kiters; ++kt) {
        if (kt + 1 < kiters) {
            stage((kt + 1) & 1, kt + 1);
            asm volatile("s_waitcnt vmcnt(4)" ::: "memory");   // wait stage(kt) only
        } else {
            asm volatile("s_waitcnt vmcnt(0)" ::: "memory");
        }
        __builtin_amdgcn_s_barrier();
        asm volatile("" ::: "memory");
        tile(kt & 1, kt);                       // no tiles skipped: all kt <= hp needed
        __builtin_amdgcn_s_barrier();
        asm volatile("" ::: "memory");
    }

    lsum += __shfl_xor(lsum, 16);
    lsum += __shfl_xor(lsum, 32);

    const float il = 1.0f / lsum;
    const int q = qw + c16;
    float* orow = out + ((size_t)(b_ * TT + q)) * CC + h_ * HS;
#pragma unroll
    for (int dt = 0; dt < 4; ++dt) {
        float4 w;
        w.x = o[dt][0] * il; w.y = o[dt][1] * il;
        w.z = o[dt][2] * il; w.w = o[dt][3] * il;
        *(float4*)(orow + dt * 16 + quad * 4) = w;
    }
}

extern "C" void kernel_launch(void* const* d_in, const int* in_sizes, int n_in,
                              void* d_out, int out_size, void* d_ws, size_t ws_size,
                              hipStream_t stream) {
    const float* x    = (const float*)d_in[0];   // [B,T,C] fp32
    const float* W    = (const float*)d_in[1];   // [C,3C] fp32
    const float* bias = (const float*)d_in[2];   // [3C] fp32
    float* out = (float*)d_out;                  // [B,T,C] fp32

    char* ws = (char*)d_ws;
    unsigned short* xb = (unsigned short*)(ws);
    unsigned short* wt = (unsigned short*)(ws + 8388608);
    unsigned short* qb = (unsigned short*)(ws + 8388608 + 6291456);
    unsigned short* kb = (unsigned short*)(ws + 8388608 + 6291456 + 8388608);
    unsigned short* vt = (unsigned short*)(ws + 8388608 + 6291456 + 2 * 8388608);

    k_cast<<<dim3(MM * CC / (256 * 4)), dim3(256), 0, stream>>>(x, xb);
    k_transpose_w<<<dim3(N3C / 32, CC / 32), dim3(256), 0, stream>>>(W, wt);
    k_gemm_qkv<<<dim3(N3C / 128, MM / 128), dim3(256), 0, stream>>>(xb, wt, bias, qb, kb, vt);
    k_attn<<<dim3(32 * 32), dim3(256), 0, stream>>>(qb, kb, vt, out);
}